// Round 3
// baseline (1222.539 us; speedup 1.0000x reference)
//
#include <hip/hip_runtime.h>
#include <hip/hip_bf16.h>

#define NAQ 35
#define NME 18
#define NN  53
#define FD  64
#define KA  24
#define KM  26
#define NC  128
#define CTXD 60

// ---- ws layout (floats) ----
#define WA_OFF 0        // 24*128 packed [W_xa|W_ua] (rows 16..23: attri half = 0)
#define WM_OFF 3072     // 26*128 packed [W_xm|W_um]
#define AV_OFF 6400     // 8*64: (type,role) first-64 halves of a-vectors
#define SV_OFF 6912     // 4*53: ctx-part of S1,S2,T1,T2 projections
#define EB_OFF 7124     // 53*56: masked bias adj>0 ? adjn*a[248] : 1e30 sentinel
#define WS_FLOATS 10092

// ---- LDS layout (floats) ----
#define S_FULLA 7124    // 35*24
#define S_FULLM 7964    // 18*26
#define S_HH    8432    // 53*128  (cols 0..63 = attri, 64..127 = heter)
#define S_RINV  15216   // 53
#define S_TOTAL 15269   // 61,076 B  (sP = 53*53 aliases [0,2809) after GEMM1)

typedef unsigned int  u32;
typedef unsigned short u16;

// dtype-agnostic float load: bf=true -> buffer is packed bf16, else fp32
__device__ __forceinline__ float ldf(const void* p, long i, bool bf) {
  if (bf) {
    u16 h = ((const u16*)p)[i];
    return __uint_as_float(((u32)h) << 16);
  }
  return ((const float*)p)[i];
}

// RNE fp32 -> bf16 bits (finite inputs only)
__device__ __forceinline__ u16 f2bf(float f) {
  u32 u = __float_as_uint(f);
  u32 r = u + 0x7FFFu + ((u >> 16) & 1u);
  return (u16)(r >> 16);
}

// sniff: is this N(0,1) buffer packed bf16?  (low halfword exponent test)
__device__ __forceinline__ bool sniff_bf16(const void* ctx) {
  const u32* w = (const u32*)ctx;
  bool ok = true;
#pragma unroll
  for (int k = 0; k < 32; ++k) {
    u32 e = (w[k] >> 7) & 0xFFu;
    ok = ok && (e >= 96u && e <= 160u);
  }
  return ok;
}

__device__ __forceinline__ float4 f4fma(float a, float4 b, float4 c) {
  c.x = fmaf(a, b.x, c.x); c.y = fmaf(a, b.y, c.y);
  c.z = fmaf(a, b.z, c.z); c.w = fmaf(a, b.w, c.w);
  return c;
}

// =======================================================================
// prep: batch-invariant tables -> ws   (runs every call; ws is re-poisoned)
// =======================================================================
__global__ void prep_kernel(
    const void* __restrict__ ctx, const void* __restrict__ adjn,
    const void* __restrict__ Wxa, const void* __restrict__ Wxm,
    const void* __restrict__ Wua, const void* __restrict__ Wum,
    const void* __restrict__ a_aa, const void* __restrict__ a_am,
    const void* __restrict__ a_ma, const void* __restrict__ a_mm,
    const int* __restrict__ adj, float* __restrict__ ws)
{
  const bool bf = sniff_bf16(ctx);
  int tid = blockIdx.x * blockDim.x + threadIdx.x;
  if (tid < 3072) {                       // Wa: [k][c], c<64 -> W_xa (k<16 else 0), c>=64 -> W_ua
    int k = tid >> 7, c = tid & 127;
    float v = (c < 64) ? ((k < 16) ? ldf(Wxa, k * 64 + c, bf) : 0.f)
                       : ldf(Wua, k * 64 + (c - 64), bf);
    ws[WA_OFF + tid] = v;
  } else if (tid < 6400) {                // Wm
    int idx = tid - WM_OFF;
    int k = idx >> 7, c = idx & 127;
    float v = (c < 64) ? ((k < 16) ? ldf(Wxm, k * 64 + c, bf) : 0.f)
                       : ldf(Wum, k * 64 + (c - 64), bf);
    ws[tid] = v;
  } else if (tid < SV_OFF) {              // AV[type*4+role][f] = a_vec first-64 half
    int idx = tid - AV_OFF;
    int tr = idx >> 6, f = idx & 63;
    const void* av; int off;
    switch (tr) {
      case 0: av = a_aa; off = 0;   break;  // A src, aqi-dst cols (aa)
      case 1: av = a_am; off = 0;   break;  // A src, meo-dst cols (am)
      case 2: av = a_aa; off = 124; break;  // A dst, aqi rows (aa)
      case 3: av = a_ma; off = 124; break;  // A dst, meo rows (ma)
      case 4: av = a_ma; off = 0;   break;  // M src, aqi-dst cols (ma)
      case 5: av = a_mm; off = 0;   break;  // M src, meo-dst cols (mm)
      case 6: av = a_am; off = 124; break;  // M dst, aqi rows (am)
      default: av = a_mm; off = 124; break; // M dst, meo rows (mm)
    }
    ws[tid] = ldf(av, off + f, bf);
  } else if (tid < EB_OFF) {              // ctx-part dots: S1,S2,T1,T2 per node
    int idx = tid - SV_OFF;
    int arr = idx / 53, i = idx - arr * 53;
    int isA = (i < NAQ);
    const void* av; int off;
    if (arr == 0)      { av = isA ? a_aa : a_ma; off = 64;  }
    else if (arr == 1) { av = isA ? a_am : a_mm; off = 64;  }
    else if (arr == 2) { av = isA ? a_aa : a_am; off = 188; }
    else               { av = isA ? a_ma : a_mm; off = 188; }
    float s = 0.f;
    for (int c = 0; c < CTXD; ++c) s += ldf(ctx, i * CTXD + c, bf) * ldf(av, off + c, bf);
    ws[tid] = s;
  } else if (tid < WS_FLOATS) {           // masked bias matrix, stride 56
    int idx = tid - EB_OFF;
    int i = idx / 56, j = idx - i * 56;
    float v = 1e30f;                      // sentinel = masked
    if (j < NN && adj[i * NN + j] > 0) {
      const void* aq = (i < NAQ) ? ((j < NAQ) ? a_aa : a_am)
                                 : ((j < NAQ) ? a_ma : a_mm);
      v = ldf(adjn, i * NN + j, bf) * ldf(aq, 248, bf);
    }
    ws[tid] = v;
  }
}

// =======================================================================
// main: one block per batch element
// =======================================================================
__global__ __launch_bounds__(256, 2) void hga_main(
    const void* __restrict__ aqi_inp, const void* __restrict__ meo_inp,
    const void* __restrict__ ctx,
    const void* __restrict__ aqi_idE, const void* __restrict__ aqi_monthE,
    const void* __restrict__ aqi_weekdayE, const void* __restrict__ aqi_hourE,
    const void* __restrict__ meo_windE, const void* __restrict__ meo_idE,
    const void* __restrict__ meo_monthE, const void* __restrict__ meo_weekdayE,
    const void* __restrict__ meo_hourE,
    const int* __restrict__ aqi_ex, const int* __restrict__ meo_ex,
    const float* __restrict__ ws, void* __restrict__ out, int B)
{
  __shared__ __align__(16) float sm[S_TOTAL];
  const int t = threadIdx.x;
  const int b = blockIdx.x;
  const bool bf = sniff_bf16(ctx);

  // ---- P0: stage precomputed tables (Wa,Wm,AV,SV) ----
  {
    const float4* src = (const float4*)ws;
    float4* dst = (float4*)sm;
    for (int v = t; v < 7124 / 4; v += 256) dst[v] = src[v];
  }
  // ---- P1: build full feature rows (inputs + embedding gathers) ----
  for (int idx = t; idx < 840 + 468; idx += 256) {
    if (idx < 840) {
      int i = idx / 24, k = idx - i * 24;
      float v;
      if (k < 16) v = ldf(aqi_inp, ((long)b * NAQ + i) * 16 + k, bf);
      else {
        int pr = (k - 16) >> 1, d = (k - 16) & 1;
        int e = aqi_ex[((long)b * NAQ + i) * 4 + pr];
        const void* tbl = (pr == 0) ? aqi_idE : (pr == 1) ? aqi_monthE
                         : (pr == 2) ? aqi_weekdayE : aqi_hourE;
        v = ldf(tbl, e * 2 + d, bf);
      }
      sm[S_FULLA + idx] = v;
    } else {
      int ix = idx - 840;
      int i = ix / 26, k = ix - i * 26;
      float v;
      if (k < 16) v = ldf(meo_inp, ((long)b * NME + i) * 16 + k, bf);
      else {
        int pr = (k - 16) >> 1, d = (k - 16) & 1;
        int e = meo_ex[((long)b * NME + i) * 5 + pr];
        const void* tbl = (pr == 0) ? meo_windE : (pr == 1) ? meo_idE
                         : (pr == 2) ? meo_monthE : (pr == 3) ? meo_weekdayE : meo_hourE;
        v = ldf(tbl, e * 2 + d, bf);
      }
      sm[S_FULLM + ix] = v;
    }
  }
  __syncthreads();

  // ---- P2: GEMM1  full(53xK) @ W(Kx128) -> sHH[53][128] ----
  {
    const int cg = t & 7, p = t >> 3;
    if (p < 27) {
      const int c0 = cg * 16;
      float4 acc0[4], acc1[4];
#pragma unroll
      for (int q = 0; q < 4; ++q) {
        acc0[q] = make_float4(0.f, 0.f, 0.f, 0.f);
        acc1[q] = make_float4(0.f, 0.f, 0.f, 0.f);
      }
      int nn0; bool two;
      if (p < 18) {
        int n0 = 2 * p; two = (n0 + 1 < NAQ); nn0 = n0;
        const float* A0 = sm + S_FULLA + n0 * KA;
        const float* A1 = two ? A0 + KA : A0;
        const float* W = sm + WA_OFF;
#pragma unroll
        for (int k = 0; k < KA; ++k) {
          float x0 = A0[k], x1 = A1[k];
          const float4* wr = (const float4*)(W + k * NC + c0);
          float4 w0 = wr[0], w1 = wr[1], w2 = wr[2], w3 = wr[3];
          acc0[0] = f4fma(x0, w0, acc0[0]); acc0[1] = f4fma(x0, w1, acc0[1]);
          acc0[2] = f4fma(x0, w2, acc0[2]); acc0[3] = f4fma(x0, w3, acc0[3]);
          acc1[0] = f4fma(x1, w0, acc1[0]); acc1[1] = f4fma(x1, w1, acc1[1]);
          acc1[2] = f4fma(x1, w2, acc1[2]); acc1[3] = f4fma(x1, w3, acc1[3]);
        }
      } else {
        int m0 = 2 * (p - 18); two = true; nn0 = NAQ + m0;
        const float* A0 = sm + S_FULLM + m0 * KM;
        const float* A1 = A0 + KM;
        const float* W = sm + WM_OFF;
#pragma unroll
        for (int k = 0; k < KM; ++k) {
          float x0 = A0[k], x1 = A1[k];
          const float4* wr = (const float4*)(W + k * NC + c0);
          float4 w0 = wr[0], w1 = wr[1], w2 = wr[2], w3 = wr[3];
          acc0[0] = f4fma(x0, w0, acc0[0]); acc0[1] = f4fma(x0, w1, acc0[1]);
          acc0[2] = f4fma(x0, w2, acc0[2]); acc0[3] = f4fma(x0, w3, acc0[3]);
          acc1[0] = f4fma(x1, w0, acc1[0]); acc1[1] = f4fma(x1, w1, acc1[1]);
          acc1[2] = f4fma(x1, w2, acc1[2]); acc1[3] = f4fma(x1, w3, acc1[3]);
        }
      }
      float4* h0 = (float4*)(sm + S_HH + nn0 * NC + c0);
      h0[0] = acc0[0]; h0[1] = acc0[1]; h0[2] = acc0[2]; h0[3] = acc0[3];
      if (two) {
        float4* h1 = (float4*)(sm + S_HH + (nn0 + 1) * NC + c0);
        h1[0] = acc1[0]; h1[1] = acc1[1]; h1[2] = acc1[2]; h1[3] = acc1[3];
      }
    }
  }
  __syncthreads();

  // ---- P3: heter-part of the 4 attention projections per node ----
  if (t < 212) {
    const int role = t & 3, node = t >> 2;
    const int type = (node < NAQ) ? 0 : 1;
    const float4* av = (const float4*)(sm + AV_OFF + (type * 4 + role) * 64);
    const float4* hh = (const float4*)(sm + S_HH + node * NC + 64);
    float s = 0.f;
#pragma unroll
    for (int q = 0; q < 16; ++q) {
      float4 a = av[q], h = hh[q];
      s += a.x * h.x + a.y * h.y + a.z * h.z + a.w * h.w;
    }
    sm[SV_OFF + role * 53 + node] += s;   // += ctx part preloaded in P0
  }
  __syncthreads();

  // ---- P4: masked leaky-relu + row softmax -> sP (aliases dead Wa region) ----
  if (t < NN) {
    const int i = t;
    const float s1 = sm[SV_OFF + i], s2 = sm[SV_OFF + 53 + i];
    const float* tb = (i < NAQ) ? (sm + SV_OFF + 106) : (sm + SV_OFF + 159);
    const float* ebrow = ws + EB_OFF + i * 56;   // L2-hot, batch-invariant
    float* prow = sm + i * 53;
    float m = -3.0e38f;
    for (int j = 0; j < NN; ++j) {
      float eb = ebrow[j];
      float e;
      if (eb > 1e29f) e = -1.0e12f;
      else {
        float r = ((j < NAQ) ? s1 : s2) + tb[j] + eb;
        e = (r > 0.f) ? r : 0.2f * r;
      }
      prow[j] = e;
      m = fmaxf(m, e);
    }
    float sum = 0.f;
    for (int j = 0; j < NN; ++j) {
      float pv = __expf(prow[j] - m);
      prow[j] = pv;
      sum += pv;
    }
    sm[S_RINV + i] = 1.f / sum;
  }
  __syncthreads();

  // ---- P5: GEMM2  att(53x53) @ attri(53x64) -> out ----
  {
    const int fg = t & 7, ip = t >> 3;
    if (ip < 27) {
      const int i0 = 2 * ip, i1 = i0 + 1;
      const bool two = (i1 < NN);
      const int c0 = fg * 8;
      const float* r0 = sm + i0 * 53;
      const float* r1 = two ? (sm + i1 * 53) : r0;
      float4 a00 = make_float4(0.f,0.f,0.f,0.f), a01 = a00, a10 = a00, a11 = a00;
      for (int j = 0; j < NN; ++j) {
        float p0 = r0[j], p1 = r1[j];
        const float4* ar = (const float4*)(sm + S_HH + j * NC + c0);
        float4 w0 = ar[0], w1 = ar[1];
        a00 = f4fma(p0, w0, a00); a01 = f4fma(p0, w1, a01);
        a10 = f4fma(p1, w0, a10); a11 = f4fma(p1, w1, a11);
      }
      float rv0 = sm[S_RINV + i0];
      float rv1 = two ? sm[S_RINV + i1] : 0.f;
#pragma unroll
      for (int rr = 0; rr < 2; ++rr) {
        if (rr == 1 && !two) break;
        const int ii = rr ? i1 : i0;
        const float rv = rr ? rv1 : rv0;
        const float4 va = rr ? a10 : a00, vb = rr ? a11 : a01;
        long off = (ii < NAQ)
          ? (long)b * (NAQ * FD) + (long)ii * FD + c0
          : (long)B * (NAQ * FD) + (long)b * (NME * FD) + (long)(ii - NAQ) * FD + c0;
        float o0 = va.x * rv, o1 = va.y * rv, o2 = va.z * rv, o3 = va.w * rv;
        float o4 = vb.x * rv, o5 = vb.y * rv, o6 = vb.z * rv, o7 = vb.w * rv;
        if (bf) {
          uint4 pk;
          pk.x = ((u32)f2bf(o1) << 16) | f2bf(o0);
          pk.y = ((u32)f2bf(o3) << 16) | f2bf(o2);
          pk.z = ((u32)f2bf(o5) << 16) | f2bf(o4);
          pk.w = ((u32)f2bf(o7) << 16) | f2bf(o6);
          *(uint4*)((u16*)out + off) = pk;
        } else {
          float4* po = (float4*)((float*)out + off);
          po[0] = make_float4(o0, o1, o2, o3);
          po[1] = make_float4(o4, o5, o6, o7);
        }
      }
    }
  }
}

extern "C" void kernel_launch(void* const* d_in, const int* in_sizes, int n_in,
                              void* d_out, int out_size, void* d_ws, size_t ws_size,
                              hipStream_t stream)
{
  const void* aqi_inp      = d_in[0];
  const void* meo_inp      = d_in[1];
  const void* ctx          = d_in[2];
  const void* adjn         = d_in[3];
  const void* aqi_idE      = d_in[4];
  const void* aqi_monthE   = d_in[5];
  const void* aqi_weekdayE = d_in[6];
  const void* aqi_hourE    = d_in[7];
  const void* meo_windE    = d_in[8];
  const void* meo_idE      = d_in[9];
  const void* meo_monthE   = d_in[10];
  const void* meo_weekdayE = d_in[11];
  const void* meo_hourE    = d_in[12];
  const void* Wxa          = d_in[13];
  const void* Wxm          = d_in[14];
  const void* Wua          = d_in[15];
  const void* Wum          = d_in[16];
  const void* a_aa         = d_in[17];
  const void* a_am         = d_in[18];
  const void* a_ma         = d_in[19];
  const void* a_mm         = d_in[20];
  const int*  aqi_ex       = (const int*)d_in[21];
  const int*  meo_ex       = (const int*)d_in[22];
  const int*  adj          = (const int*)d_in[23];
  float* ws = (float*)d_ws;
  const int B = in_sizes[0] / (NAQ * 16);

  hipLaunchKernelGGL(prep_kernel, dim3((WS_FLOATS + 255) / 256), dim3(256), 0, stream,
                     ctx, adjn, Wxa, Wxm, Wua, Wum, a_aa, a_am, a_ma, a_mm, adj, ws);
  hipLaunchKernelGGL(hga_main, dim3(B), dim3(256), 0, stream,
                     aqi_inp, meo_inp, ctx, aqi_idE, aqi_monthE, aqi_weekdayE, aqi_hourE,
                     meo_windE, meo_idE, meo_monthE, meo_weekdayE, meo_hourE,
                     aqi_ex, meo_ex, ws, d_out, B);
}

// Round 4
// 429.803 us; speedup vs baseline: 2.8444x; 2.8444x over previous
//
#include <hip/hip_runtime.h>
#include <hip/hip_bf16.h>

#define NAQ 35
#define NME 18
#define NN  53
#define FD  64
#define KA  24
#define KM  26
#define NC  128
#define CTXD 60
#define PERB 8          // batch elements per block

// ---- ws layout (floats) ----
#define WA_OFF 0        // 24*128 packed [W_xa|W_ua]
#define WM_OFF 3072     // 26*128 packed [W_xm|W_um]
#define AV_OFF 6400     // 8*64 a-vector first-64 halves
#define SV_OFF 6912     // 4*53 ctx-part of projections
#define EB_OFF 7124     // 53*56 masked bias (1e30 sentinel)
#define WS_FLOATS 10092

// ---- LDS layout (floats); [0,7124) mirrors ws ----
#define L_FULLA 7124    // 35 rows, stride 25
#define L_FULLM 8000    // 18 rows, stride 27
#define L_SVW   8488    // 4*53 per-element projections
#define L_MR    8700    // 53 row-max + 53 rinv
#define L_HH    8808    // 53 rows, stride 132 (cols 0..63 attri, 64..127 heter)
#define HH_STR  132
#define S_TOTAL 15804   // 63,216 B -> 2 blocks/CU

typedef unsigned int   u32;
typedef unsigned short u16;

__device__ __forceinline__ float ldf(const void* p, long i, bool bf) {
  if (bf) { u16 h = ((const u16*)p)[i]; return __uint_as_float(((u32)h) << 16); }
  return ((const float*)p)[i];
}
__device__ __forceinline__ u16 f2bf(float f) {
  u32 u = __float_as_uint(f);
  return (u16)((u + 0x7FFFu + ((u >> 16) & 1u)) >> 16);
}
__device__ __forceinline__ bool sniff_bf16(const void* ctx) {
  const u32* w = (const u32*)ctx;
  bool ok = true;
#pragma unroll
  for (int k = 0; k < 32; ++k) {
    u32 e = (w[k] >> 7) & 0xFFu;
    ok = ok && (e >= 96u && e <= 160u);
  }
  return ok;
}
__device__ __forceinline__ float4 f4fma(float a, float4 b, float4 c) {
  c.x = fmaf(a, b.x, c.x); c.y = fmaf(a, b.y, c.y);
  c.z = fmaf(a, b.z, c.z); c.w = fmaf(a, b.w, c.w);
  return c;
}

// =======================================================================
// prep: batch-invariant tables -> ws (unchanged from round 3 — verified)
// =======================================================================
__global__ void prep_kernel(
    const void* __restrict__ ctx, const void* __restrict__ adjn,
    const void* __restrict__ Wxa, const void* __restrict__ Wxm,
    const void* __restrict__ Wua, const void* __restrict__ Wum,
    const void* __restrict__ a_aa, const void* __restrict__ a_am,
    const void* __restrict__ a_ma, const void* __restrict__ a_mm,
    const int* __restrict__ adj, float* __restrict__ ws)
{
  const bool bf = sniff_bf16(ctx);
  int tid = blockIdx.x * blockDim.x + threadIdx.x;
  if (tid < 3072) {
    int k = tid >> 7, c = tid & 127;
    float v = (c < 64) ? ((k < 16) ? ldf(Wxa, k * 64 + c, bf) : 0.f)
                       : ldf(Wua, k * 64 + (c - 64), bf);
    ws[WA_OFF + tid] = v;
  } else if (tid < 6400) {
    int idx = tid - WM_OFF;
    int k = idx >> 7, c = idx & 127;
    float v = (c < 64) ? ((k < 16) ? ldf(Wxm, k * 64 + c, bf) : 0.f)
                       : ldf(Wum, k * 64 + (c - 64), bf);
    ws[tid] = v;
  } else if (tid < SV_OFF) {
    int idx = tid - AV_OFF;
    int tr = idx >> 6, f = idx & 63;
    const void* av; int off;
    switch (tr) {
      case 0: av = a_aa; off = 0;   break;
      case 1: av = a_am; off = 0;   break;
      case 2: av = a_aa; off = 124; break;
      case 3: av = a_ma; off = 124; break;
      case 4: av = a_ma; off = 0;   break;
      case 5: av = a_mm; off = 0;   break;
      case 6: av = a_am; off = 124; break;
      default: av = a_mm; off = 124; break;
    }
    ws[tid] = ldf(av, off + f, bf);
  } else if (tid < EB_OFF) {
    int idx = tid - SV_OFF;
    int arr = idx / 53, i = idx - arr * 53;
    int isA = (i < NAQ);
    const void* av; int off;
    if (arr == 0)      { av = isA ? a_aa : a_ma; off = 64;  }
    else if (arr == 1) { av = isA ? a_am : a_mm; off = 64;  }
    else if (arr == 2) { av = isA ? a_aa : a_am; off = 188; }
    else               { av = isA ? a_ma : a_mm; off = 188; }
    float s = 0.f;
    for (int c = 0; c < CTXD; ++c) s += ldf(ctx, i * CTXD + c, bf) * ldf(av, off + c, bf);
    ws[tid] = s;
  } else if (tid < WS_FLOATS) {
    int idx = tid - EB_OFF;
    int i = idx / 56, j = idx - i * 56;
    float v = 1e30f;
    if (j < NN && adj[i * NN + j] > 0) {
      const void* aq = (i < NAQ) ? ((j < NAQ) ? a_aa : a_am)
                                 : ((j < NAQ) ? a_ma : a_mm);
      v = ldf(adjn, i * NN + j, bf) * ldf(aq, 248, bf);
    }
    ws[tid] = v;
  }
}

// =======================================================================
// main: one block = PERB batch elements; tables staged once
// =======================================================================
__global__ __launch_bounds__(256, 2) void hga_main(
    const void* __restrict__ aqi_inp, const void* __restrict__ meo_inp,
    const void* __restrict__ ctx,
    const void* __restrict__ aqi_idE, const void* __restrict__ aqi_monthE,
    const void* __restrict__ aqi_weekdayE, const void* __restrict__ aqi_hourE,
    const void* __restrict__ meo_windE, const void* __restrict__ meo_idE,
    const void* __restrict__ meo_monthE, const void* __restrict__ meo_weekdayE,
    const void* __restrict__ meo_hourE,
    const int* __restrict__ aqi_ex, const int* __restrict__ meo_ex,
    const float* __restrict__ ws, void* __restrict__ out, int B)
{
  __shared__ __align__(16) float sm[S_TOTAL];
  const int t = threadIdx.x;
  const bool bf = sniff_bf16(ctx);

  // ---- P0 (once): stage WA, WM, AV, SVC  (7124 floats, ws-mirrored) ----
  {
    const float4* src = (const float4*)ws;
    float4* dst = (float4*)sm;
    for (int v = t; v < 7124 / 4; v += 256) dst[v] = src[v];
  }
  __syncthreads();

  for (int e = 0; e < PERB; ++e) {
    const int b = blockIdx.x * PERB + e;
    if (b >= B) break;                       // uniform within block

    // ---- P1: feature rows (padded strides 25 / 27) ----
    for (int idx = t; idx < 840 + 468; idx += 256) {
      if (idx < 840) {
        int i = idx / 24, k = idx - i * 24;
        float v;
        if (k < 16) v = ldf(aqi_inp, ((long)b * NAQ + i) * 16 + k, bf);
        else {
          int pr = (k - 16) >> 1, d = (k - 16) & 1;
          int ee = aqi_ex[((long)b * NAQ + i) * 4 + pr];
          const void* tbl = (pr == 0) ? aqi_idE : (pr == 1) ? aqi_monthE
                           : (pr == 2) ? aqi_weekdayE : aqi_hourE;
          v = ldf(tbl, ee * 2 + d, bf);
        }
        sm[L_FULLA + i * 25 + k] = v;
      } else {
        int ix = idx - 840;
        int i = ix / 26, k = ix - i * 26;
        float v;
        if (k < 16) v = ldf(meo_inp, ((long)b * NME + i) * 16 + k, bf);
        else {
          int pr = (k - 16) >> 1, d = (k - 16) & 1;
          int ee = meo_ex[((long)b * NME + i) * 5 + pr];
          const void* tbl = (pr == 0) ? meo_windE : (pr == 1) ? meo_idE
                           : (pr == 2) ? meo_monthE : (pr == 3) ? meo_weekdayE : meo_hourE;
          v = ldf(tbl, ee * 2 + d, bf);
        }
        sm[L_FULLM + i * 27 + k] = v;
      }
    }
    __syncthreads();

    // ---- P2: GEMM1  full(53xK) @ W(Kx128) -> HH (padded stride 132) ----
    {
      const int cg = t & 7, p = t >> 3;
      if (p < 27) {
        const int c0 = cg * 16;
        float4 a00 = make_float4(0.f,0.f,0.f,0.f), a01 = a00, a02 = a00, a03 = a00;
        float4 a10 = a00, a11 = a00, a12 = a00, a13 = a00;
        const float *A0, *A1, *Wb; int K, nn0; bool two;
        if (p < 18) {
          int n0 = 2 * p; two = (n0 + 1 < NAQ); nn0 = n0;
          A0 = sm + L_FULLA + n0 * 25; A1 = two ? A0 + 25 : A0;
          Wb = sm + WA_OFF; K = KA;
        } else {
          int m0 = 2 * (p - 18); two = true; nn0 = NAQ + m0;
          A0 = sm + L_FULLM + m0 * 27; A1 = A0 + 27;
          Wb = sm + WM_OFF; K = KM;
        }
#pragma unroll 2
        for (int k = 0; k < K; ++k) {
          float x0 = A0[k], x1 = A1[k];
          const float4* wr = (const float4*)(Wb + k * NC + c0);
          float4 w0 = wr[0], w1 = wr[1], w2 = wr[2], w3 = wr[3];
          a00 = f4fma(x0, w0, a00); a01 = f4fma(x0, w1, a01);
          a02 = f4fma(x0, w2, a02); a03 = f4fma(x0, w3, a03);
          a10 = f4fma(x1, w0, a10); a11 = f4fma(x1, w1, a11);
          a12 = f4fma(x1, w2, a12); a13 = f4fma(x1, w3, a13);
        }
        float4* h0 = (float4*)(sm + L_HH + nn0 * HH_STR + c0);
        h0[0] = a00; h0[1] = a01; h0[2] = a02; h0[3] = a03;
        if (two) {
          float4* h1 = (float4*)(sm + L_HH + (nn0 + 1) * HH_STR + c0);
          h1[0] = a10; h1[1] = a11; h1[2] = a12; h1[3] = a13;
        }
      }
    }
    __syncthreads();

    // ---- P3: 4 attention projections per node: SVW = SVC + dot(AV, heter) ----
    if (t < 212) {
      const int role = t & 3, node = t >> 2;
      const int type = (node < NAQ) ? 0 : 1;
      const float4* av = (const float4*)(sm + AV_OFF + (type * 4 + role) * 64);
      const float4* hh = (const float4*)(sm + L_HH + node * HH_STR + 64);
      float s = 0.f;
#pragma unroll
      for (int q = 0; q < 16; ++q) {
        float4 a = av[q], h = hh[q];
        s += a.x * h.x + a.y * h.y + a.z * h.z + a.w * h.w;
      }
      sm[L_SVW + role * 53 + node] = sm[SV_OFF + role * 53 + node] + s;
    }
    __syncthreads();

    // ---- P4: row max + 1/sum only (no prow materialization) ----
    if (t < NN) {
      const int i = t;
      const float s1 = sm[L_SVW + i], s2 = sm[L_SVW + 53 + i];
      const float* tb = sm + L_SVW + ((i < NAQ) ? 106 : 159);
      const float* ebrow = ws + EB_OFF + i * 56;     // L1/L2-hot
      float m = -3.0e38f;
#pragma unroll 4
      for (int j = 0; j < NN; ++j) {
        float eb = ebrow[j];
        float r = ((j < NAQ) ? s1 : s2) + tb[j] + eb;
        float ev = (eb > 1e29f) ? -1.0e12f : ((r > 0.f) ? r : 0.2f * r);
        m = fmaxf(m, ev);
      }
      float sum = 0.f;
#pragma unroll 4
      for (int j = 0; j < NN; ++j) {
        float eb = ebrow[j];
        float r = ((j < NAQ) ? s1 : s2) + tb[j] + eb;
        float ev = (eb > 1e29f) ? -1.0e12f : ((r > 0.f) ? r : 0.2f * r);
        sum += __expf(ev - m);
      }
      sm[L_MR + i] = m;
      sm[L_MR + 53 + i] = 1.f / sum;
    }
    __syncthreads();

    // ---- P5: out[i,:] = (softmax row) @ attri, P recomputed on the fly ----
    {
      const int fg = t & 7, ip = t >> 3;
      if (ip < 27) {
        const int i0 = 2 * ip, i1 = i0 + 1;
        const bool two = (i1 < NN);
        const int c0 = fg * 8;
        const float s10 = sm[L_SVW + i0],      s20 = sm[L_SVW + 53 + i0];
        const float s11 = two ? sm[L_SVW + i1] : 0.f;
        const float s21 = two ? sm[L_SVW + 53 + i1] : 0.f;
        const int   ts0 = (i0 < NAQ) ? 106 : 159;
        const int   ts1 = (i1 < NAQ) ? 106 : 159;
        const float m0 = sm[L_MR + i0];
        const float m1 = two ? sm[L_MR + i1] : 0.f;
        const float* eb0 = ws + EB_OFF + i0 * 56;
        const float* eb1 = ws + EB_OFF + i1 * 56;
        float4 a00 = make_float4(0.f,0.f,0.f,0.f), a01 = a00, a10 = a00, a11 = a00;
#pragma unroll 2
        for (int j = 0; j < NN; ++j) {
          float tA = sm[L_SVW + ts0 + j];
          float tBv = sm[L_SVW + ts1 + j];
          float b0 = eb0[j], b1 = eb1[j];
          float r0 = ((j < NAQ) ? s10 : s20) + tA + b0;
          float r1 = ((j < NAQ) ? s11 : s21) + tBv + b1;
          float e0 = (b0 > 1e29f) ? -1.0e12f : ((r0 > 0.f) ? r0 : 0.2f * r0);
          float e1 = (b1 > 1e29f) ? -1.0e12f : ((r1 > 0.f) ? r1 : 0.2f * r1);
          float p0 = __expf(e0 - m0);
          float p1 = __expf(e1 - m1);
          const float4* ar = (const float4*)(sm + L_HH + j * HH_STR + c0);
          float4 w0 = ar[0], w1 = ar[1];
          a00 = f4fma(p0, w0, a00); a01 = f4fma(p0, w1, a01);
          a10 = f4fma(p1, w0, a10); a11 = f4fma(p1, w1, a11);
        }
        float rv0 = sm[L_MR + 53 + i0];
        float rv1 = two ? sm[L_MR + 53 + i1] : 0.f;
#pragma unroll
        for (int rr = 0; rr < 2; ++rr) {
          if (rr == 1 && !two) break;
          const int ii = rr ? i1 : i0;
          const float rv = rr ? rv1 : rv0;
          const float4 va = rr ? a10 : a00, vb = rr ? a11 : a01;
          long off = (ii < NAQ)
            ? (long)b * (NAQ * FD) + (long)ii * FD + c0
            : (long)B * (NAQ * FD) + (long)b * (NME * FD) + (long)(ii - NAQ) * FD + c0;
          float o0 = va.x * rv, o1 = va.y * rv, o2 = va.z * rv, o3 = va.w * rv;
          float o4 = vb.x * rv, o5 = vb.y * rv, o6 = vb.z * rv, o7 = vb.w * rv;
          if (bf) {
            uint4 pk;
            pk.x = ((u32)f2bf(o1) << 16) | f2bf(o0);
            pk.y = ((u32)f2bf(o3) << 16) | f2bf(o2);
            pk.z = ((u32)f2bf(o5) << 16) | f2bf(o4);
            pk.w = ((u32)f2bf(o7) << 16) | f2bf(o6);
            *(uint4*)((u16*)out + off) = pk;
          } else {
            float4* po = (float4*)((float*)out + off);
            po[0] = make_float4(o0, o1, o2, o3);
            po[1] = make_float4(o4, o5, o6, o7);
          }
        }
      }
    }
    __syncthreads();   // HH/FULL/SVW/MR reused by next element
  }
}

extern "C" void kernel_launch(void* const* d_in, const int* in_sizes, int n_in,
                              void* d_out, int out_size, void* d_ws, size_t ws_size,
                              hipStream_t stream)
{
  const void* aqi_inp      = d_in[0];
  const void* meo_inp      = d_in[1];
  const void* ctx          = d_in[2];
  const void* adjn         = d_in[3];
  const void* aqi_idE      = d_in[4];
  const void* aqi_monthE   = d_in[5];
  const void* aqi_weekdayE = d_in[6];
  const void* aqi_hourE    = d_in[7];
  const void* meo_windE    = d_in[8];
  const void* meo_idE      = d_in[9];
  const void* meo_monthE   = d_in[10];
  const void* meo_weekdayE = d_in[11];
  const void* meo_hourE    = d_in[12];
  const void* Wxa          = d_in[13];
  const void* Wxm          = d_in[14];
  const void* Wua          = d_in[15];
  const void* Wum          = d_in[16];
  const void* a_aa         = d_in[17];
  const void* a_am         = d_in[18];
  const void* a_ma         = d_in[19];
  const void* a_mm         = d_in[20];
  const int*  aqi_ex       = (const int*)d_in[21];
  const int*  meo_ex       = (const int*)d_in[22];
  const int*  adj          = (const int*)d_in[23];
  float* ws = (float*)d_ws;
  const int B = in_sizes[0] / (NAQ * 16);

  hipLaunchKernelGGL(prep_kernel, dim3((WS_FLOATS + 255) / 256), dim3(256), 0, stream,
                     ctx, adjn, Wxa, Wxm, Wua, Wum, a_aa, a_am, a_ma, a_mm, adj, ws);
  hipLaunchKernelGGL(hga_main, dim3((B + PERB - 1) / PERB), dim3(256), 0, stream,
                     aqi_inp, meo_inp, ctx, aqi_idE, aqi_monthE, aqi_weekdayE, aqi_hourE,
                     meo_windE, meo_idE, meo_monthE, meo_weekdayE, meo_hourE,
                     aqi_ex, meo_ex, ws, d_out, B);
}

// Round 5
// 270.827 us; speedup vs baseline: 4.5141x; 1.5870x over previous
//
#include <hip/hip_runtime.h>
#include <hip/hip_bf16.h>

#define NAQ 35
#define NME 18
#define NN  53
#define FD  64
#define CTXD 60
#define PERB 2          // batch elements per block

// ---- ws layout (floats) ----
#define WXA_OFF 0       // 16*64 W_xa
#define WXM_OFF 1024    // 16*64 W_xm
#define CV_OFF  2048    // 8*28 folded heter-projection vectors C[tr][k]
#define SVC_OFF 2272    // 4*53 ctx-part of projections
#define EB_OFF  2484    // 53*56 masked bias (1e30 sentinel)
#define WS_FLOATS 5452

// ---- LDS layout (floats); [0,2484) mirrors ws ----
#define L_WX    0       // 2048 (WXA @0, WXM @1024)
#define L_CV    2048    // 224 (stride 28)
#define L_SVC   2272    // 212
#define L_FULLA 2484    // 35 rows, stride 25
#define L_FULLM 3359    // 18 rows, stride 27
#define L_SVW   3845    // 4*53
#define L_MR    4057    // 53 max + 53 rinv
#define L_AT    4164    // 53 rows, stride 68 (attri), 16B-aligned
#define S_TOTAL 7768    // 31,072 B -> 5 blocks/CU

typedef unsigned int   u32;
typedef unsigned short u16;

__device__ __forceinline__ float ldf(const void* p, long i, bool bf) {
  if (bf) { u16 h = ((const u16*)p)[i]; return __uint_as_float(((u32)h) << 16); }
  return ((const float*)p)[i];
}
__device__ __forceinline__ u16 f2bf(float f) {
  u32 u = __float_as_uint(f);
  return (u16)((u + 0x7FFFu + ((u >> 16) & 1u)) >> 16);
}
__device__ __forceinline__ bool sniff_bf16(const void* ctx) {
  const u32* w = (const u32*)ctx;
  bool ok = true;
#pragma unroll
  for (int k = 0; k < 32; ++k) {
    u32 e = (w[k] >> 7) & 0xFFu;
    ok = ok && (e >= 96u && e <= 160u);
  }
  return ok;
}
__device__ __forceinline__ float4 f4fma(float a, float4 b, float4 c) {
  c.x = fmaf(a, b.x, c.x); c.y = fmaf(a, b.y, c.y);
  c.z = fmaf(a, b.z, c.z); c.w = fmaf(a, b.w, c.w);
  return c;
}

// =======================================================================
// prep: batch-invariant tables -> ws
// =======================================================================
__global__ void prep_kernel(
    const void* __restrict__ ctx, const void* __restrict__ adjn,
    const void* __restrict__ Wxa, const void* __restrict__ Wxm,
    const void* __restrict__ Wua, const void* __restrict__ Wum,
    const void* __restrict__ a_aa, const void* __restrict__ a_am,
    const void* __restrict__ a_ma, const void* __restrict__ a_mm,
    const int* __restrict__ adj, float* __restrict__ ws)
{
  const bool bf = sniff_bf16(ctx);
  int tid = blockIdx.x * blockDim.x + threadIdx.x;
  if (tid < 1024) {                        // W_xa 16x64
    ws[WXA_OFF + tid] = ldf(Wxa, tid, bf);
  } else if (tid < 2048) {                 // W_xm 16x64
    ws[tid] = ldf(Wxm, tid - 1024, bf);
  } else if (tid < CV_OFF + 224) {         // C[tr][k] = sum_f Wu[k][f]*AV_tr[f]
    int idx = tid - CV_OFF;
    int tr = idx / 28, k = idx - tr * 28;
    int K = (tr < 4) ? 24 : 26;
    float v = 0.f;
    if (k < K) {
      const void* Wu = (tr < 4) ? Wua : Wum;
      const void* av; int off;
      switch (tr) {
        case 0: av = a_aa; off = 0;   break;  // A-node src, aqi-col rows
        case 1: av = a_am; off = 0;   break;  // A-node src, meo-col
        case 2: av = a_aa; off = 124; break;  // A-node dst (aqi rows)
        case 3: av = a_ma; off = 124; break;  // A-node dst (meo rows)
        case 4: av = a_ma; off = 0;   break;  // M-node src, aqi-col
        case 5: av = a_mm; off = 0;   break;  // M-node src, meo-col
        case 6: av = a_am; off = 124; break;  // M-node dst (aqi rows)
        default: av = a_mm; off = 124; break; // M-node dst (meo rows)
      }
      float s = 0.f;
      for (int f = 0; f < 64; ++f) s += ldf(Wu, k * 64 + f, bf) * ldf(av, off + f, bf);
      v = s;
    }
    ws[tid] = v;
  } else if (tid < EB_OFF) {               // ctx-part dots
    int idx = tid - SVC_OFF;
    int arr = idx / 53, i = idx - arr * 53;
    int isA = (i < NAQ);
    const void* av; int off;
    if (arr == 0)      { av = isA ? a_aa : a_ma; off = 64;  }
    else if (arr == 1) { av = isA ? a_am : a_mm; off = 64;  }
    else if (arr == 2) { av = isA ? a_aa : a_am; off = 188; }
    else               { av = isA ? a_ma : a_mm; off = 188; }
    float s = 0.f;
    for (int c = 0; c < CTXD; ++c) s += ldf(ctx, i * CTXD + c, bf) * ldf(av, off + c, bf);
    ws[tid] = s;
  } else if (tid < WS_FLOATS) {            // masked bias, stride 56
    int idx = tid - EB_OFF;
    int i = idx / 56, j = idx - i * 56;
    float v = 1e30f;
    if (j < NN && adj[i * NN + j] > 0) {
      const void* aq = (i < NAQ) ? ((j < NAQ) ? a_aa : a_am)
                                 : ((j < NAQ) ? a_ma : a_mm);
      v = ldf(adjn, i * NN + j, bf) * ldf(aq, 248, bf);
    }
    ws[tid] = v;
  }
}

// =======================================================================
// main: one block = PERB batch elements
// =======================================================================
__global__ __launch_bounds__(256, 5) void hga_main(
    const void* __restrict__ aqi_inp, const void* __restrict__ meo_inp,
    const void* __restrict__ ctx,
    const void* __restrict__ aqi_idE, const void* __restrict__ aqi_monthE,
    const void* __restrict__ aqi_weekdayE, const void* __restrict__ aqi_hourE,
    const void* __restrict__ meo_windE, const void* __restrict__ meo_idE,
    const void* __restrict__ meo_monthE, const void* __restrict__ meo_weekdayE,
    const void* __restrict__ meo_hourE,
    const int* __restrict__ aqi_ex, const int* __restrict__ meo_ex,
    const float* __restrict__ ws, void* __restrict__ out, int B)
{
  __shared__ __align__(16) float sm[S_TOTAL];
  const int t = threadIdx.x;
  const bool bf = sniff_bf16(ctx);

  // ---- P0 (once): stage WX, CV, SVC (2484 floats, ws-mirrored) ----
  {
    const float4* src = (const float4*)ws;
    float4* dst = (float4*)sm;
    for (int v = t; v < 2484 / 4; v += 256) dst[v] = src[v];
  }
  __syncthreads();

  for (int e = 0; e < PERB; ++e) {
    const int b = blockIdx.x * PERB + e;
    if (b >= B) break;

    // ---- P1: feature rows (padded strides 25 / 27) ----
    for (int idx = t; idx < 840 + 468; idx += 256) {
      if (idx < 840) {
        int i = idx / 24, k = idx - i * 24;
        float v;
        if (k < 16) v = ldf(aqi_inp, ((long)b * NAQ + i) * 16 + k, bf);
        else {
          int pr = (k - 16) >> 1, d = (k - 16) & 1;
          int ee = aqi_ex[((long)b * NAQ + i) * 4 + pr];
          const void* tbl = (pr == 0) ? aqi_idE : (pr == 1) ? aqi_monthE
                           : (pr == 2) ? aqi_weekdayE : aqi_hourE;
          v = ldf(tbl, ee * 2 + d, bf);
        }
        sm[L_FULLA + i * 25 + k] = v;
      } else {
        int ix = idx - 840;
        int i = ix / 26, k = ix - i * 26;
        float v;
        if (k < 16) v = ldf(meo_inp, ((long)b * NME + i) * 16 + k, bf);
        else {
          int pr = (k - 16) >> 1, d = (k - 16) & 1;
          int ee = meo_ex[((long)b * NME + i) * 5 + pr];
          const void* tbl = (pr == 0) ? meo_windE : (pr == 1) ? meo_idE
                           : (pr == 2) ? meo_monthE : (pr == 3) ? meo_weekdayE : meo_hourE;
          v = ldf(tbl, ee * 2 + d, bf);
        }
        sm[L_FULLM + i * 27 + k] = v;
      }
    }
    __syncthreads();

    // ---- P2: attri = inp(53x16) @ Wx(16x64) -> L_AT (stride 68) ----
    {
      const int r = t >> 2, cg = t & 3;
      if (r < NN) {
        const int c0 = cg * 16;
        const float* A = (r < NAQ) ? sm + L_FULLA + r * 25
                                   : sm + L_FULLM + (r - NAQ) * 27;
        const float* W = (r < NAQ) ? sm + L_WX : sm + L_WX + 1024;
        float4 a0 = make_float4(0.f,0.f,0.f,0.f), a1 = a0, a2 = a0, a3 = a0;
#pragma unroll
        for (int k = 0; k < 16; ++k) {
          float x = A[k];
          const float4* wr = (const float4*)(W + k * 64 + c0);
          a0 = f4fma(x, wr[0], a0); a1 = f4fma(x, wr[1], a1);
          a2 = f4fma(x, wr[2], a2); a3 = f4fma(x, wr[3], a3);
        }
        float4* h = (float4*)(sm + L_AT + r * 68 + c0);
        h[0] = a0; h[1] = a1; h[2] = a2; h[3] = a3;
      }
      // ---- P3 (same phase; reads only full rows): svw via folded C-vectors ----
      const int node = t >> 2, role = t & 3;
      if (node < NN) {
        const bool isA = (node < NAQ);
        const int K = isA ? 24 : 26;
        const float* F = isA ? sm + L_FULLA + node * 25
                             : sm + L_FULLM + (node - NAQ) * 27;
        const float* C = sm + L_CV + ((isA ? 0 : 4) + role) * 28;
        float s = 0.f;
        for (int k = 0; k < K; ++k) s = fmaf(F[k], C[k], s);
        sm[L_SVW + role * 53 + node] = sm[L_SVC + role * 53 + node] + s;
      }
    }
    __syncthreads();

    // ---- P4: row softmax stats, (row x quarter) + shfl_xor merge ----
    {
      const int r = t >> 2, q = t & 3;
      if (r < NN) {
        const float s1 = sm[L_SVW + r], s2 = sm[L_SVW + 53 + r];
        const float* tb = sm + L_SVW + ((r < NAQ) ? 106 : 159);
        const float* ebrow = ws + EB_OFF + r * 56;
        const int j0 = q * 14;
        const int jn = (q == 3) ? 11 : 14;
        float m = -3.0e38f;
        for (int jj = 0; jj < jn; ++jj) {
          int j = j0 + jj;
          float eb = ebrow[j];
          float rr = ((j < NAQ) ? s1 : s2) + tb[j] + eb;
          float ev = (eb > 1e29f) ? -1.0e12f : ((rr > 0.f) ? rr : 0.2f * rr);
          m = fmaxf(m, ev);
        }
        float s = 0.f;
        for (int jj = 0; jj < jn; ++jj) {
          int j = j0 + jj;
          float eb = ebrow[j];
          float rr = ((j < NAQ) ? s1 : s2) + tb[j] + eb;
          float ev = (eb > 1e29f) ? -1.0e12f : ((rr > 0.f) ? rr : 0.2f * rr);
          s += __expf(ev - m);
        }
#pragma unroll
        for (int d = 1; d <= 2; d <<= 1) {
          float om = __shfl_xor(m, d, 64);
          float os = __shfl_xor(s, d, 64);
          float nm = fmaxf(m, om);
          s = s * __expf(m - nm) + os * __expf(om - nm);
          m = nm;
        }
        if (q == 0) {
          sm[L_MR + r] = m;
          sm[L_MR + 53 + r] = 1.f / s;
        }
      }
    }
    __syncthreads();

    // ---- P5: out[i,:] = softmax(row) @ attri (P recomputed on the fly) ----
    {
      const int fg = t & 7, ip = t >> 3;
      if (ip < 27) {
        const int i0 = 2 * ip, i1 = i0 + 1;
        const bool two = (i1 < NN);
        const int c0 = fg * 8;
        const float s10 = sm[L_SVW + i0],      s20 = sm[L_SVW + 53 + i0];
        const float s11 = two ? sm[L_SVW + i1] : 0.f;
        const float s21 = two ? sm[L_SVW + 53 + i1] : 0.f;
        const int   ts0 = (i0 < NAQ) ? 106 : 159;
        const int   ts1 = (i1 < NAQ) ? 106 : 159;
        const float m0 = sm[L_MR + i0];
        const float m1 = two ? sm[L_MR + i1] : 0.f;
        const float* eb0 = ws + EB_OFF + i0 * 56;
        const float* eb1 = ws + EB_OFF + i1 * 56;
        float4 a00 = make_float4(0.f,0.f,0.f,0.f), a01 = a00, a10 = a00, a11 = a00;
#pragma unroll 2
        for (int j = 0; j < NN; ++j) {
          float tA  = sm[L_SVW + ts0 + j];
          float tBv = sm[L_SVW + ts1 + j];
          float b0 = eb0[j], b1 = eb1[j];
          float r0 = ((j < NAQ) ? s10 : s20) + tA + b0;
          float r1 = ((j < NAQ) ? s11 : s21) + tBv + b1;
          float e0 = (b0 > 1e29f) ? -1.0e12f : ((r0 > 0.f) ? r0 : 0.2f * r0);
          float e1 = (b1 > 1e29f) ? -1.0e12f : ((r1 > 0.f) ? r1 : 0.2f * r1);
          float p0 = __expf(e0 - m0);
          float p1 = __expf(e1 - m1);
          const float4* ar = (const float4*)(sm + L_AT + j * 68 + c0);
          float4 w0 = ar[0], w1 = ar[1];
          a00 = f4fma(p0, w0, a00); a01 = f4fma(p0, w1, a01);
          a10 = f4fma(p1, w0, a10); a11 = f4fma(p1, w1, a11);
        }
        float rv0 = sm[L_MR + 53 + i0];
        float rv1 = two ? sm[L_MR + 53 + i1] : 0.f;
#pragma unroll
        for (int rr = 0; rr < 2; ++rr) {
          if (rr == 1 && !two) break;
          const int ii = rr ? i1 : i0;
          const float rv = rr ? rv1 : rv0;
          const float4 va = rr ? a10 : a00, vb = rr ? a11 : a01;
          long off = (ii < NAQ)
            ? (long)b * (NAQ * FD) + (long)ii * FD + c0
            : (long)B * (NAQ * FD) + (long)b * (NME * FD) + (long)(ii - NAQ) * FD + c0;
          float o0 = va.x * rv, o1 = va.y * rv, o2 = va.z * rv, o3 = va.w * rv;
          float o4 = vb.x * rv, o5 = vb.y * rv, o6 = vb.z * rv, o7 = vb.w * rv;
          if (bf) {
            uint4 pk;
            pk.x = ((u32)f2bf(o1) << 16) | f2bf(o0);
            pk.y = ((u32)f2bf(o3) << 16) | f2bf(o2);
            pk.z = ((u32)f2bf(o5) << 16) | f2bf(o4);
            pk.w = ((u32)f2bf(o7) << 16) | f2bf(o6);
            *(uint4*)((u16*)out + off) = pk;
          } else {
            float4* po = (float4*)((float*)out + off);
            po[0] = make_float4(o0, o1, o2, o3);
            po[1] = make_float4(o4, o5, o6, o7);
          }
        }
      }
    }
    __syncthreads();   // LDS reused by next element
  }
}

extern "C" void kernel_launch(void* const* d_in, const int* in_sizes, int n_in,
                              void* d_out, int out_size, void* d_ws, size_t ws_size,
                              hipStream_t stream)
{
  const void* aqi_inp      = d_in[0];
  const void* meo_inp      = d_in[1];
  const void* ctx          = d_in[2];
  const void* adjn         = d_in[3];
  const void* aqi_idE      = d_in[4];
  const void* aqi_monthE   = d_in[5];
  const void* aqi_weekdayE = d_in[6];
  const void* aqi_hourE    = d_in[7];
  const void* meo_windE    = d_in[8];
  const void* meo_idE      = d_in[9];
  const void* meo_monthE   = d_in[10];
  const void* meo_weekdayE = d_in[11];
  const void* meo_hourE    = d_in[12];
  const void* Wxa          = d_in[13];
  const void* Wxm          = d_in[14];
  const void* Wua          = d_in[15];
  const void* Wum          = d_in[16];
  const void* a_aa         = d_in[17];
  const void* a_am         = d_in[18];
  const void* a_ma         = d_in[19];
  const void* a_mm         = d_in[20];
  const int*  aqi_ex       = (const int*)d_in[21];
  const int*  meo_ex       = (const int*)d_in[22];
  const int*  adj          = (const int*)d_in[23];
  float* ws = (float*)d_ws;
  const int B = in_sizes[0] / (NAQ * 16);

  hipLaunchKernelGGL(prep_kernel, dim3((WS_FLOATS + 255) / 256), dim3(256), 0, stream,
                     ctx, adjn, Wxa, Wxm, Wua, Wum, a_aa, a_am, a_ma, a_mm, adj, ws);
  hipLaunchKernelGGL(hga_main, dim3((B + PERB - 1) / PERB), dim3(256), 0, stream,
                     aqi_inp, meo_inp, ctx, aqi_idE, aqi_monthE, aqi_weekdayE, aqi_hourE,
                     meo_windE, meo_idE, meo_monthE, meo_weekdayE, meo_hourE,
                     aqi_ex, meo_ex, ws, d_out, B);
}